// Round 4
// baseline (48.574 us; speedup 1.0000x reference)
//
#include <hip/hip_runtime.h>

// Delay-logistic DDE, forward Euler, d independent scalar components.
// x_{i+1} = x_i * m_i,  m_i = (1+a) - a*th1*y_i,  a = dt*th0,
// y_i = x_{i-100} (constant history x_0 for i < 100).
// Output: out[j*(N+1) + t] = x_t  (row-major [d, N+1]).
//
// Block = (64-component chunk) x (time-group g). Recompute groups 0..g from
// x_0, then emit group g's 100 columns via FIVE 20-column LDS transposes
// (5.25 KB LDS). Single-wave blocks + in-order DS pipe => NO barriers.
//
// ROUND-3 BUG FIXED HERE: the phase loop was a runtime loop, so h[c*TPH+k]
// was runtime-indexed -> h[100] spilled to scratch (VGPR_Count=64, +290 MB
// of scratch traffic in FETCH/WRITE_SIZE). Phase loop is now fully unrolled
// so every h index is compile-time and h stays in registers (rule #20).

constexpr int NT   = 1000;          // N steps (setup_inputs: N=1000)
constexpr int NTAU = 100;           // steps per delay interval
constexpr int NGRP = NT / NTAU;     // 10 groups
constexpr int NP1  = NT + 1;        // 1001 columns per row
constexpr int CPB  = 64;            // components per block == block size (1 wave)
constexpr int TPH  = 20;            // time-columns per staging phase
constexpr int NPH  = NTAU / TPH;    // 5 phases
constexpr int LSTR = TPH + 1;       // 21 dwords: gcd(21,32)=1 -> conflict-free stage
constexpr int RPI  = 3;             // rows per store instr (3*20 = 60 lanes)
constexpr int NSI  = (CPB + RPI - 1) / RPI;  // 22 store instrs per phase

__global__ __launch_bounds__(CPB, 4)   // cap 128 VGPR -> 16 waves/CU
void ndde_kernel(const float* __restrict__ x0,
                 const float* __restrict__ tau,
                 const float* __restrict__ params,
                 float* __restrict__ out)
{
    __shared__ float lds[CPB][LSTR];
    const int tid = threadIdx.x;
    // g = NGRP-1 - blockIdx.y: longest-recompute blocks dispatch FIRST.
    const int g = (NGRP - 1) - (int)blockIdx.y;
    const long long jbase = (long long)blockIdx.x * CPB;

    const float dt = 0.01f * tau[0];
    const float a  = dt * params[0];        // dt * theta0
    const float q  = -(a * params[1]);      // -dt*theta0*theta1
    const float p  = 1.0f + a;

    float x = x0[jbase + tid];
    // h[k] at start of group gg holds x_{100*(gg-1)+k}; constant history gg=0.
    float h[NTAU];
#pragma unroll
    for (int k = 0; k < NTAU; ++k) h[k] = x;

    // Recompute groups 0..g; after iteration gg, h[k] = x_{100*gg+k}.
    for (int gg = 0; gg <= g; ++gg) {
#pragma unroll
        for (int k = 0; k < NTAU; ++k) {
            const float y = h[k];           // x_{i-100}
            const float m = fmaf(q, y, p);  // (1+a) - a*th1*y
            h[k] = x;                       // becomes x_{100*gg+k}
            x *= m;
        }
    }
    // h[k] = x_{100g+k}: output columns t = 100g .. 100g+99.

    // Drain lane mapping: lane = (row-offset lq, time lt) within a phase.
    const int lq = tid / TPH;               // 0..3 (lq==3 -> inactive in drain)
    const int lt = tid - lq * TPH;          // 0..19
    const long long colbase = (long long)g * NTAU;
    const float* lrow = &lds[lq][lt];
    float* gp0 = out + (jbase + lq) * NP1 + colbase + lt;

#pragma unroll   // CRITICAL: compile-time c -> h[] stays in registers
    for (int c = 0; c < NPH; ++c) {
        // Stage 20 columns: lane tid writes its row (stride 21 -> conflict-free).
#pragma unroll
        for (int k = 0; k < TPH; ++k) lds[tid][k] = h[c * TPH + k];
        // No barrier: single wave, DS pipe is in-order per wave.

        // Dense transpose drain: instr i covers rows 3i..3i+2, cols lt.
        float* gp = gp0 + c * TPH;
#pragma unroll
        for (int i = 0; i < NSI; ++i) {
            const int r = RPI * i + lq;
            if (lq < RPI && r < CPB)
                gp[(long long)RPI * i * NP1] = lrow[RPI * i * LSTR];
        }
    }

    // Final column t = N written by the g = NGRP-1 blocks (x = x_1000 here).
    if (g == NGRP - 1)
        out[(jbase + tid) * NP1 + NT] = x;
}

extern "C" void kernel_launch(void* const* d_in, const int* in_sizes, int n_in,
                              void* d_out, int out_size, void* d_ws, size_t ws_size,
                              hipStream_t stream) {
    const float* x0     = (const float*)d_in[0];
    const float* tau    = (const float*)d_in[1];
    const float* params = (const float*)d_in[2];
    float* out = (float*)d_out;
    const int d = in_sizes[0];              // 32768
    const int chunks = d / CPB;             // 512
    dim3 grid(chunks, NGRP);
    ndde_kernel<<<grid, CPB, 0, stream>>>(x0, tau, params, out);
}

// Round 5
// 48.437 us; speedup vs baseline: 1.0028x; 1.0028x over previous
//
#include <hip/hip_runtime.h>

// Delay-logistic DDE, forward Euler, d independent scalar components.
// x_{i+1} = x_i * m_i,  m_i = (1+a) - a*th1*y_i,  a = dt*th0,
// y_i = x_{i-100} (constant history x_0 for i < 100).
// Output: out[j*(N+1) + t] = x_t  (row-major [d, N+1]).
//
// Block = (64-component chunk) x (time-group g). Recompute groups 0..g from
// x_0, then emit group g's 100 columns via FIVE 20-column LDS transposes
// (5.25 KB LDS). Single-wave blocks + in-order DS pipe => NO barriers.
//
// ROUND-4 POST-MORTEM: __launch_bounds__(64,4) set amdgpu-waves-per-eu=4
// (VGPR cap 128); the scheduler's pressure ESTIMATE for 100 live h values +
// 5 unrolled drain phases overshot the cap and spilled the whole array
// (VGPR_Count=64, FETCH 220 MB of scratch reads). Round 2, identical compute
// structure WITHOUT the min-waves arg, provably kept h in registers. So:
// plain __launch_bounds__(CPB) — let the allocator take ~115 VGPR.

constexpr int NT   = 1000;          // N steps (setup_inputs: N=1000)
constexpr int NTAU = 100;           // steps per delay interval
constexpr int NGRP = NT / NTAU;     // 10 groups
constexpr int NP1  = NT + 1;        // 1001 columns per row
constexpr int CPB  = 64;            // components per block == block size (1 wave)
constexpr int TPH  = 20;            // time-columns per staging phase
constexpr int NPH  = NTAU / TPH;    // 5 phases
constexpr int LSTR = TPH + 1;       // 21 dwords: gcd(21,32)=1 -> conflict-free stage
constexpr int RPI  = 3;             // rows per store instr (3*20 = 60 lanes)
constexpr int NSI  = (CPB + RPI - 1) / RPI;  // 22 store instrs per phase

__global__ __launch_bounds__(CPB)   // NO min-waves arg: avoid pressure-cap spill
void ndde_kernel(const float* __restrict__ x0,
                 const float* __restrict__ tau,
                 const float* __restrict__ params,
                 float* __restrict__ out)
{
    __shared__ float lds[CPB][LSTR];
    const int tid = threadIdx.x;
    // g = NGRP-1 - blockIdx.y: longest-recompute blocks dispatch FIRST.
    const int g = (NGRP - 1) - (int)blockIdx.y;
    const long long jbase = (long long)blockIdx.x * CPB;

    const float dt = 0.01f * tau[0];
    const float a  = dt * params[0];        // dt * theta0
    const float q  = -(a * params[1]);      // -dt*theta0*theta1
    const float p  = 1.0f + a;

    float x = x0[jbase + tid];
    // h[k] at start of group gg holds x_{100*(gg-1)+k}; constant history gg=0.
    float h[NTAU];
#pragma unroll
    for (int k = 0; k < NTAU; ++k) h[k] = x;

    // Recompute groups 0..g; after iteration gg, h[k] = x_{100*gg+k}.
    for (int gg = 0; gg <= g; ++gg) {
#pragma unroll
        for (int k = 0; k < NTAU; ++k) {
            const float y = h[k];           // x_{i-100}
            const float m = fmaf(q, y, p);  // (1+a) - a*th1*y
            h[k] = x;                       // becomes x_{100*gg+k}
            x *= m;
        }
    }
    // h[k] = x_{100g+k}: output columns t = 100g .. 100g+99.

    // Drain lane mapping: lane = (row-offset lq, time lt) within a phase.
    const int lq = tid / TPH;               // 0..3 (lq==3 -> inactive in drain)
    const int lt = tid - lq * TPH;          // 0..19
    const long long colbase = (long long)g * NTAU;
    const float* lrow = &lds[lq][lt];
    float* gp0 = out + (jbase + lq) * NP1 + colbase + lt;

#pragma unroll   // compile-time c -> h[] indices stay static (rule #20)
    for (int c = 0; c < NPH; ++c) {
        // Stage 20 columns: lane tid writes its row (stride 21 -> conflict-free).
#pragma unroll
        for (int k = 0; k < TPH; ++k) lds[tid][k] = h[c * TPH + k];
        // No barrier: single wave, DS pipe is in-order per wave.

        // Dense transpose drain: instr i covers rows 3i..3i+2, cols lt.
        float* gp = gp0 + c * TPH;
#pragma unroll
        for (int i = 0; i < NSI; ++i) {
            const int r = RPI * i + lq;
            if (lq < RPI && r < CPB)
                gp[(long long)RPI * i * NP1] = lrow[RPI * i * LSTR];
        }
    }

    // Final column t = N written by the g = NGRP-1 blocks (x = x_1000 here).
    if (g == NGRP - 1)
        out[(jbase + tid) * NP1 + NT] = x;
}

extern "C" void kernel_launch(void* const* d_in, const int* in_sizes, int n_in,
                              void* d_out, int out_size, void* d_ws, size_t ws_size,
                              hipStream_t stream) {
    const float* x0     = (const float*)d_in[0];
    const float* tau    = (const float*)d_in[1];
    const float* params = (const float*)d_in[2];
    float* out = (float*)d_out;
    const int d = in_sizes[0];              // 32768
    const int chunks = d / CPB;             // 512
    dim3 grid(chunks, NGRP);
    ndde_kernel<<<grid, CPB, 0, stream>>>(x0, tau, params, out);
}

// Round 7
// 46.798 us; speedup vs baseline: 1.0379x; 1.0350x over previous
//
#include <hip/hip_runtime.h>

// Delay-logistic DDE, forward Euler, d independent scalar components.
// x_{i+1} = x_i * m_i,  m_i = (1+a) - a*th1*y_i,  a = dt*th0,
// y_i = x_{i-100} (constant history x_0 for i < 100).
// Output: out[j*(N+1) + t] = x_t  (row-major [d, N+1]).
//
// Block = (64-component chunk) x (time-group g). Recompute groups 0..g from
// x_0, then emit group g's 100 columns via five 20-column LDS transposes
// (5.25 KB LDS). h[100] kept in VGPRs via macro-LITERAL indices + min-waves=1
// (rounds 3-5: backend's default 8-waves/SIMD target force-spilled h).
//
// ROUND-6 POST-MORTEM (absmax 0.10): the transpose is CROSS-LANE, and the
// per-thread memory model lets the compiler reorder phase c+1's ds_writes
// above phase c's ds_reads when they don't alias LANE-LOCALLY (true for most
// lanes of a transpose). With h in registers + flat macro body it did exactly
// that. Fix: explicit LDS-only ordering point at every stage<->drain boundary:
// sched_barrier + "s_waitcnt lgkmcnt(0)" w/ memory clobber + sched_barrier.
// NOT __syncthreads(): that would force vmcnt(0) and drain the global-store
// queue every phase (the round-1 limiter). Global stores stay in flight.

constexpr int NT   = 1000;          // N steps (setup_inputs: N=1000)
constexpr int NTAU = 100;           // steps per delay interval
constexpr int NGRP = NT / NTAU;     // 10 groups
constexpr int NP1  = NT + 1;        // 1001 columns per row
constexpr int CPB  = 64;            // components per block == block size (1 wave)
constexpr int TPH  = 20;            // time-columns per staging phase
constexpr int LSTR = TPH + 1;       // 21 dwords: gcd(21,32)=1 -> conflict-free stage
constexpr int RPI  = 3;             // rows per store instr (3*20 = 60 lanes)
constexpr int NSI  = 22;            // store instrs per phase (ceil(64/3))

// Literal-index repetition macros: every F(K) gets a constant expression.
#define R5(F,B)  F(B) F((B)+1) F((B)+2) F((B)+3) F((B)+4)
#define R20(F,B) R5(F,B) R5(F,(B)+5) R5(F,(B)+10) R5(F,(B)+15)
#define R100(F)  R20(F,0) R20(F,20) R20(F,40) R20(F,60) R20(F,80)

// LDS-only ordering point: compiler fence (memory clobber + sched_barrier)
// and hardware wait on the DS pipe. Does NOT wait on vmcnt -> global stores
// keep streaming.
#define LDS_ORDER() do {                                    \
    __builtin_amdgcn_sched_barrier(0);                      \
    asm volatile("s_waitcnt lgkmcnt(0)" ::: "memory");      \
    __builtin_amdgcn_sched_barrier(0);                      \
} while (0)

__global__ __launch_bounds__(CPB, 1)   // min 1 wave/EU: 512-VGPR budget, no forced spill
void ndde_kernel(const float* __restrict__ x0,
                 const float* __restrict__ tau,
                 const float* __restrict__ params,
                 float* __restrict__ out)
{
    __shared__ float lds[CPB][LSTR];
    const int tid = threadIdx.x;
    // g = NGRP-1 - blockIdx.y: longest-recompute blocks dispatch FIRST.
    const int g = (NGRP - 1) - (int)blockIdx.y;
    const long long jbase = (long long)blockIdx.x * CPB;

    const float dt = 0.01f * tau[0];
    const float a  = dt * params[0];        // dt * theta0
    const float q  = -(a * params[1]);      // -dt*theta0*theta1
    const float p  = 1.0f + a;

    float x = x0[jbase + tid];
    float h[NTAU];                          // history; lives in VGPRs
#define INIT_H(K) h[(K)] = x;
    R100(INIT_H)

    // Recompute groups 0..g; after iteration gg, h[k] = x_{100*gg+k}.
    for (int gg = 0; gg <= g; ++gg) {
#define STEP(K) { const float y_ = h[(K)]; h[(K)] = x; x *= fmaf(q, y_, p); }
        R100(STEP)
    }
    // h[k] = x_{100g+k}: output columns t = 100g .. 100g+99.

    // Drain lane mapping: lane = (row-offset lq, time lt) within a phase.
    const int lq = tid / TPH;               // 0..3 (lq==3 inactive in drain)
    const int lt = tid - lq * TPH;          // 0..19
    const float* lrow = &lds[lq][lt];
    float* gp0 = out + (jbase + lq) * NP1 + (long long)g * NTAU + lt;

    // Transpose drain for one staged 20-column tile.
    auto drain = [&](int c) {
        float* gp = gp0 + c * TPH;
#pragma unroll
        for (int i = 0; i < NSI; ++i) {
            if (lq < RPI && RPI * i + lq < CPB)
                gp[(long long)(RPI * i) * NP1] = lrow[RPI * i * LSTR];
        }
    };

    // Five stage+drain phases with explicit cross-lane ordering points.
#define STG0(K) lds[tid][(K)] = h[(K)];
#define STG1(K) lds[tid][(K)] = h[20+(K)];
#define STG2(K) lds[tid][(K)] = h[40+(K)];
#define STG3(K) lds[tid][(K)] = h[60+(K)];
#define STG4(K) lds[tid][(K)] = h[80+(K)];
    R20(STG0, 0)  LDS_ORDER();  drain(0);  LDS_ORDER();
    R20(STG1, 0)  LDS_ORDER();  drain(1);  LDS_ORDER();
    R20(STG2, 0)  LDS_ORDER();  drain(2);  LDS_ORDER();
    R20(STG3, 0)  LDS_ORDER();  drain(3);  LDS_ORDER();
    R20(STG4, 0)  LDS_ORDER();  drain(4);

    // Final column t = N written by the g = NGRP-1 blocks (x = x_1000 here).
    if (g == NGRP - 1)
        out[(jbase + tid) * NP1 + NT] = x;
}

extern "C" void kernel_launch(void* const* d_in, const int* in_sizes, int n_in,
                              void* d_out, int out_size, void* d_ws, size_t ws_size,
                              hipStream_t stream) {
    const float* x0     = (const float*)d_in[0];
    const float* tau    = (const float*)d_in[1];
    const float* params = (const float*)d_in[2];
    float* out = (float*)d_out;
    const int d = in_sizes[0];              // 32768
    const int chunks = d / CPB;             // 512
    dim3 grid(chunks, NGRP);                // x=chunk: same-chunk groups share XCD
    ndde_kernel<<<grid, CPB, 0, stream>>>(x0, tau, params, out);
}

// Round 8
// 40.564 us; speedup vs baseline: 1.1975x; 1.1537x over previous
//
#include <hip/hip_runtime.h>

// Delay-logistic DDE, forward Euler, d independent scalar components.
// x_{i+1} = x_i * m_i,  m_i = (1+a) - a*th1*y_i,  a = dt*th0,
// y_i = x_{i-100} (constant history x_0 for i < 100).
// Output: out[j*(N+1) + t] = x_t  (row-major [d, N+1]).
//
// Block = (64-component chunk) x (50-step window w, w=0..19). Each block
// recomputes windows 0..w from x_0 (delay ring h[100] in VGPRs), stages its
// 50-column tile to LDS (13.06 KB -> 12 blocks/CU), ONE LDS fence, then
// drains with contiguous 200B row stores (lanes along time).
//
// Verified-bad patterns avoided:
//  - spill (rounds 2-5, VGPR=64, +67MB HBM writes): (CPB,1) lifts the
//    backend's 8-waves/SIMD VGPR target; ALL h indices are macro-LITERAL
//    (SROA-proof; no reliance on unroll pragmas).
//  - cross-lane LDS reorder (round 6, absmax 0.10): one explicit LDS_ORDER
//    between stage and drain. No trailing fence needed: LDS written once.
//  - per-phase fences + scattered 80B drain segments (rounds 3-5,7): single
//    stage+drain, row-contiguous stores (round 2's proven pattern).

constexpr int NT   = 1000;          // N steps (setup_inputs: N=1000)
constexpr int NTAU = 100;          // steps per delay interval (ring size)
constexpr int W    = 50;            // steps (=output cols) per window
constexpr int NW   = NT / W;        // 20 windows
constexpr int NP1  = NT + 1;        // 1001 columns per row
constexpr int CPB  = 64;            // components per block == block size (1 wave)
constexpr int LSTR = W + 1;         // 51 dwords: 51 mod 32 = 19, odd -> conflict-free

// Literal-index repetition macros.
#define R5(F,B)   F(B) F((B)+1) F((B)+2) F((B)+3) F((B)+4)
#define R25(F,B)  R5(F,B) R5(F,(B)+5) R5(F,(B)+10) R5(F,(B)+15) R5(F,(B)+20)
#define R50(F,B)  R25(F,B) R25(F,(B)+25)
#define R100(F)   R50(F,0) R50(F,50)

// LDS-only ordering point: compiler fence + DS-pipe drain. Does NOT wait on
// vmcnt -> global stores keep streaming.
#define LDS_ORDER() do {                                    \
    __builtin_amdgcn_sched_barrier(0);                      \
    asm volatile("s_waitcnt lgkmcnt(0)" ::: "memory");      \
    __builtin_amdgcn_sched_barrier(0);                      \
} while (0)

__global__ __launch_bounds__(CPB, 1)   // min 1 wave/EU: full 512-VGPR budget
void ndde_kernel(const float* __restrict__ x0,
                 const float* __restrict__ tau,
                 const float* __restrict__ params,
                 float* __restrict__ out)
{
    __shared__ float lds[CPB][LSTR];
    const int tid = threadIdx.x;
    // w = NW-1 - blockIdx.y: longest-recompute blocks dispatch FIRST.
    const int w = (NW - 1) - (int)blockIdx.y;
    const long long jbase = (long long)blockIdx.x * CPB;

    const float dt = 0.01f * tau[0];
    const float a  = dt * params[0];        // dt * theta0
    const float q  = -(a * params[1]);      // -dt*theta0*theta1
    const float p  = 1.0f + a;

    float x = x0[jbase + tid];
    float h[NTAU];                          // delay ring; lives in VGPRs
#define INIT_H(K) h[(K)] = x;
    R100(INIT_H)

    // Step i (= 50*ww + k): ring slot s = i mod 100 = k + 50*(ww&1).
    // Read y = h[s] (= x_{i-100}, or x_0 untouched for i<100), then h[s] = x_i.
#define STEP_E(K) { const float y_ = h[(K)];      h[(K)]      = x; x *= fmaf(q, y_, p); }
#define STEP_O(K) { const float y_ = h[50+(K)];   h[50+(K)]   = x; x *= fmaf(q, y_, p); }

    // Windows 0..w: pairs (even, odd), then a lone even window if w is even.
#pragma clang loop unroll(disable)
    for (int ww = 0; ww + 1 <= w; ww += 2) {
        R50(STEP_E, 0)
        R50(STEP_O, 0)
    }
    if ((w & 1) == 0) { R50(STEP_E, 0) }
    // Window w's outputs x_{50w+k} now sit in ring half 50*(w&1) + k.

    // Stage the 50-column tile (stride 51: 2-way bank alias max = free).
#define STG_E(K) lds[tid][(K)] = h[(K)];
#define STG_O(K) lds[tid][(K)] = h[50+(K)];
    if ((w & 1) == 0) { R50(STG_E, 0) } else { R50(STG_O, 0) }

    LDS_ORDER();   // cross-lane stage->drain boundary (the round-6 lesson)

    // Drain: lanes run along TIME (contiguous 200B per row store).
    const long long t0 = (long long)w * W;
    if (tid < W) {
        float* gp = out + jbase * NP1 + t0 + tid;
#pragma unroll 8
        for (int r = 0; r < CPB; ++r)
            gp[(long long)r * NP1] = lds[r][tid];
    }

    // Final column t = N written by the w = NW-1 blocks (x = x_1000 here).
    if (w == NW - 1)
        out[(jbase + tid) * NP1 + NT] = x;
}

extern "C" void kernel_launch(void* const* d_in, const int* in_sizes, int n_in,
                              void* d_out, int out_size, void* d_ws, size_t ws_size,
                              hipStream_t stream) {
    const float* x0     = (const float*)d_in[0];
    const float* tau    = (const float*)d_in[1];
    const float* params = (const float*)d_in[2];
    float* out = (float*)d_out;
    const int d = in_sizes[0];              // 32768
    const int chunks = d / CPB;             // 512
    dim3 grid(chunks, NW);                  // 10240 one-wave blocks
    ndde_kernel<<<grid, CPB, 0, stream>>>(x0, tau, params, out);
}

// Round 9
// 38.379 us; speedup vs baseline: 1.2657x; 1.0569x over previous
//
#include <hip/hip_runtime.h>

// Delay-logistic DDE, forward Euler, d independent scalar components.
// x_{i+1} = x_i * m_i,  m_i = (1+a) - a*th1*y_i,  a = dt*th0,
// y_i = x_{i-100} (constant history x_0 for i < 100).
// Output: out[j*(N+1) + t] = x_t  (row-major [d, N+1]).
//
// Round-9 A/B vs round 8: window back to W=100 (grid 512x10) -> total
// recompute VALU halves (10500 -> 5500 steps/component, ~15 -> ~7.9 us of
// per-CU issue); LDS stays 13.06 KB by draining in TWO 50-column phases from
// one reused buffer. Everything else is round 8's verified machinery:
//  - h[100] in VGPRs: macro-LITERAL indices (SROA-proof) + (CPB,1) to lift
//    the backend's default waves/SIMD VGPR target (rounds 2-5 spilled).
//  - LDS-only fences (lgkmcnt(0) + sched_barrier + memory clobber) at every
//    cross-lane stage<->drain boundary (round 6: reorder corrupted data);
//    NOT __syncthreads (would force vmcnt(0), stalling the store stream).
//  - Drain: lanes along TIME, contiguous 200 B row stores; 4004 B row stride
//    has odd dword phase -> vector (x2/x4) stores are impossible; 50-lane
//    b32 row stores are the optimal shape.

constexpr int NT   = 1000;          // N steps (setup_inputs: N=1000)
constexpr int NTAU = 100;           // steps per delay interval (= window)
constexpr int NGRP = NT / NTAU;     // 10 groups
constexpr int NP1  = NT + 1;        // 1001 columns per row
constexpr int CPB  = 64;            // components per block == block size (1 wave)
constexpr int HW   = 50;            // drain phase width (half window)
constexpr int LSTR = HW + 1;        // 51 dwords: odd stride -> conflict-free

// Literal-index repetition macros.
#define R5(F,B)   F(B) F((B)+1) F((B)+2) F((B)+3) F((B)+4)
#define R25(F,B)  R5(F,B) R5(F,(B)+5) R5(F,(B)+10) R5(F,(B)+15) R5(F,(B)+20)
#define R50(F,B)  R25(F,B) R25(F,(B)+25)
#define R100(F)   R50(F,0) R50(F,50)

// LDS-only ordering point: compiler fence + DS-pipe drain; does NOT touch
// vmcnt, so global stores keep streaming.
#define LDS_ORDER() do {                                    \
    __builtin_amdgcn_sched_barrier(0);                      \
    asm volatile("s_waitcnt lgkmcnt(0)" ::: "memory");      \
    __builtin_amdgcn_sched_barrier(0);                      \
} while (0)

__global__ __launch_bounds__(CPB, 1)   // min 1 wave/EU: full 512-VGPR budget
void ndde_kernel(const float* __restrict__ x0,
                 const float* __restrict__ tau,
                 const float* __restrict__ params,
                 float* __restrict__ out)
{
    __shared__ float lds[CPB][LSTR];   // 13,056 B
    const int tid = threadIdx.x;
    // g = NGRP-1 - blockIdx.y: longest-recompute blocks dispatch FIRST.
    const int g = (NGRP - 1) - (int)blockIdx.y;
    const long long jbase = (long long)blockIdx.x * CPB;

    const float dt = 0.01f * tau[0];
    const float a  = dt * params[0];        // dt * theta0
    const float q  = -(a * params[1]);      // -dt*theta0*theta1
    const float p  = 1.0f + a;

    float x = x0[jbase + tid];
    float h[NTAU];                          // history; lives in VGPRs
#define INIT_H(K) h[(K)] = x;
    R100(INIT_H)

    // Recompute groups 0..g; after iteration gg, h[k] = x_{100*gg+k}.
#define STEP(K) { const float y_ = h[(K)]; h[(K)] = x; x *= fmaf(q, y_, p); }
#pragma clang loop unroll(disable)
    for (int gg = 0; gg <= g; ++gg) {
        R100(STEP)
    }
    // h[k] = x_{100g+k}: output columns t = 100g .. 100g+99.

    const long long t0 = (long long)g * NTAU;
    float* gp0 = out + jbase * NP1 + t0 + tid;

    // ---- phase A: columns 0..49 ----
#define STG_A(K) lds[tid][(K)] = h[(K)];
    R50(STG_A, 0)
    LDS_ORDER();                      // stage -> drain (cross-lane RAW)
    if (tid < HW) {
#pragma unroll 8
        for (int r = 0; r < CPB; ++r)
            gp0[(long long)r * NP1] = lds[r][tid];
    }
    LDS_ORDER();                      // drain -> restage (cross-lane WAR)

    // ---- phase B: columns 50..99 ----
#define STG_B(K) lds[tid][(K)] = h[50+(K)];
    R50(STG_B, 0)
    LDS_ORDER();                      // stage -> drain
    if (tid < HW) {
        float* gpB = gp0 + HW;
#pragma unroll 8
        for (int r = 0; r < CPB; ++r)
            gpB[(long long)r * NP1] = lds[r][tid];
    }

    // Final column t = N written by the g = NGRP-1 blocks (x = x_1000 here).
    if (g == NGRP - 1)
        out[(jbase + tid) * NP1 + NT] = x;
}

extern "C" void kernel_launch(void* const* d_in, const int* in_sizes, int n_in,
                              void* d_out, int out_size, void* d_ws, size_t ws_size,
                              hipStream_t stream) {
    const float* x0     = (const float*)d_in[0];
    const float* tau    = (const float*)d_in[1];
    const float* params = (const float*)d_in[2];
    float* out = (float*)d_out;
    const int d = in_sizes[0];              // 32768
    const int chunks = d / CPB;             // 512
    dim3 grid(chunks, NGRP);                // 5120 one-wave blocks; same-chunk
    ndde_kernel<<<grid, CPB, 0, stream>>>(x0, tau, params, out);  // groups share an XCD (512%8==0)
}